// Round 2
// baseline (123.997 us; speedup 1.0000x reference)
//
#include <hip/hip_runtime.h>

#define GS   8                  // S-table grid points per axis (8x8 bilinear; err ~2e-6 in output)
#define GB   64                 // bias-table grid points
#define HDIM 256
#define SOFF (4 * GS * GS * 12) // float offset of bias tables in ws

// ---------------------------------------------------------------------------
// Kernel 1: tabulate the pair MLP S(x0,x1) on a GS x GS grid for each of the 4
// layers (entry padded to 12 floats), and the two bias MLPs bq(m), bp(m) on a
// GB grid (entry padded to 4 floats).
//
// v3: the HDIM x HDIM second layer is K-split across the 4 waves and
// vectorized:  thread t = (s = t>>6 k-slice, g = t&63 neuron quad) loads
// float4 W1[k][4g..4g+3] — 4 iterations x 16 dwordx4 in flight (v2 was 16
// iterations x 16 dword).  The poison fill evicts L2+L3 every iteration, so
// W1 is HBM-latency (~900 cyc) on first touch: shortening the dependent-load
// chain 4x is the lever (this kernel is latency-bound, not BW-bound).
// Partial accumulators are combined through LDS, then the layer-3 shuffle
// reduction is unchanged.
// ---------------------------------------------------------------------------
__global__ __launch_bounds__(256) void build_tables(
    const float* __restrict__ sW0, const float* __restrict__ sb0,
    const float* __restrict__ sW1, const float* __restrict__ sb1,
    const float* __restrict__ sW2, const float* __restrict__ sb2,
    const float* __restrict__ qW0, const float* __restrict__ qb0,
    const float* __restrict__ qW1, const float* __restrict__ qb1,
    const float* __restrict__ qW2, const float* __restrict__ qb2,
    const float* __restrict__ kW0, const float* __restrict__ kb0,
    const float* __restrict__ kW1, const float* __restrict__ kb1,
    const float* __restrict__ kW2, const float* __restrict__ kb2,
    float* __restrict__ ws)
{
    const int t  = threadIdx.x;
    const int bx = blockIdx.x;
    const int g  = t & 63;   // neuron quad: outputs 4g..4g+3
    const int s  = t >> 6;   // k-slice: k in [64s, 64s+64)
    const int k0 = s << 6;

    __shared__ float  h0s[HDIM];
    __shared__ float4 red2[4][64];
    __shared__ float  h1s[HDIM];
    __shared__ float  red[4][9];

    if (bx < 256) {
        // ---------------- S table: block = (layer l, grid point pt) ----------
        const int l  = bx >> 6;
        const int pt = bx & 63;
        const float* W0 = sW0 + l * 2 * HDIM;
        const float* W1 = sW1 + l * HDIM * HDIM;

        const float x0 = (float)(pt >> 3) * (1.0f / (GS - 1)); // first MLP input (m_j axis)
        const float x1 = (float)(pt & 7)  * (1.0f / (GS - 1)); // second MLP input (m_i axis)
        h0s[t] = tanhf(x0 * W0[t] + x1 * W0[HDIM + t] + sb0[l * HDIM + t]);
        __syncthreads();

        // second layer, K-split: acc4[c] = sum_{k in slice} h0[k] * W1[k][4g+c]
        float4 acc4 = make_float4(0.f, 0.f, 0.f, 0.f);
        const float* W1c = W1 + 4 * g;
        for (int kk = 0; kk < 64; kk += 16) {
            float4 w4[16];
            #pragma unroll
            for (int u = 0; u < 16; u++)
                w4[u] = *(const float4*)&W1c[(k0 + kk + u) * HDIM];
            #pragma unroll
            for (int u = 0; u < 16; u++) {
                float h = h0s[k0 + kk + u];        // wave-uniform broadcast
                acc4.x += h * w4[u].x;
                acc4.y += h * w4[u].y;
                acc4.z += h * w4[u].z;
                acc4.w += h * w4[u].w;
            }
        }
        red2[s][g] = acc4;
        __syncthreads();
        if (t < 64) {
            float4 a = red2[0][t], b = red2[1][t], c = red2[2][t], d = red2[3][t];
            float4 bb = *(const float4*)&sb1[l * HDIM + 4 * t];
            float4 h1;
            h1.x = tanhf(a.x + b.x + c.x + d.x + bb.x);
            h1.y = tanhf(a.y + b.y + c.y + d.y + bb.y);
            h1.z = tanhf(a.z + b.z + c.z + d.z + bb.z);
            h1.w = tanhf(a.w + b.w + c.w + d.w + bb.w);
            *(float4*)&h1s[4 * t] = h1;
        }
        __syncthreads();

        // third layer + block reduce
        const float h1 = h1s[t];
        float part[9];
        #pragma unroll
        for (int o = 0; o < 9; o++) part[o] = h1 * sW2[(l * HDIM + t) * 9 + o];
        #pragma unroll
        for (int off = 32; off >= 1; off >>= 1) {
            #pragma unroll
            for (int o = 0; o < 9; o++) part[o] += __shfl_xor(part[o], off);
        }
        const int wave = t >> 6;
        if ((t & 63) == 0) {
            #pragma unroll
            for (int o = 0; o < 9; o++) red[wave][o] = part[o];
        }
        __syncthreads();
        if (t < 9) {
            float sv = red[0][t] + red[1][t] + red[2][t] + red[3][t] + sb2[l * 9 + t];
            ws[((l * GS + (pt >> 3)) * GS + (pt & 7)) * 12 + t] = tanhf(sv);
        }
    } else {
        // ---------------- bias tables: bq (which=0) / bp (which=1) ----------
        const int bb    = bx - 256;
        const int which = bb >> 6;
        const int pt    = bb & 63;
        const float* W0 = which ? kW0 : qW0;
        const float* B0 = which ? kb0 : qb0;
        const float* W1 = which ? kW1 : qW1;
        const float* B1 = which ? kb1 : qb1;
        const float* W2 = which ? kW2 : qW2;
        const float* B2 = which ? kb2 : qb2;

        const float x = (float)pt * (1.0f / (GB - 1));
        h0s[t] = tanhf(x * W0[t] + B0[t]);
        __syncthreads();

        float4 acc4 = make_float4(0.f, 0.f, 0.f, 0.f);
        const float* W1c = W1 + 4 * g;
        for (int kk = 0; kk < 64; kk += 16) {
            float4 w4[16];
            #pragma unroll
            for (int u = 0; u < 16; u++)
                w4[u] = *(const float4*)&W1c[(k0 + kk + u) * HDIM];
            #pragma unroll
            for (int u = 0; u < 16; u++) {
                float h = h0s[k0 + kk + u];
                acc4.x += h * w4[u].x;
                acc4.y += h * w4[u].y;
                acc4.z += h * w4[u].z;
                acc4.w += h * w4[u].w;
            }
        }
        red2[s][g] = acc4;
        __syncthreads();
        if (t < 64) {
            float4 a = red2[0][t], b = red2[1][t], c = red2[2][t], d = red2[3][t];
            float4 bbv = *(const float4*)&B1[4 * t];
            float4 h1;
            h1.x = tanhf(a.x + b.x + c.x + d.x + bbv.x);
            h1.y = tanhf(a.y + b.y + c.y + d.y + bbv.y);
            h1.z = tanhf(a.z + b.z + c.z + d.z + bbv.z);
            h1.w = tanhf(a.w + b.w + c.w + d.w + bbv.w);
            *(float4*)&h1s[4 * t] = h1;
        }
        __syncthreads();

        const float h1 = h1s[t];
        float part[3];
        #pragma unroll
        for (int o = 0; o < 3; o++) part[o] = h1 * W2[t * 3 + o];
        #pragma unroll
        for (int off = 32; off >= 1; off >>= 1) {
            #pragma unroll
            for (int o = 0; o < 3; o++) part[o] += __shfl_xor(part[o], off);
        }
        const int wave = t >> 6;
        if ((t & 63) == 0) {
            #pragma unroll
            for (int o = 0; o < 3; o++) red[wave][o] = part[o];
        }
        __syncthreads();
        if (t < 3) {
            float sv = red[0][t] + red[1][t] + red[2][t] + red[3][t] + B2[t];
            ws[SOFF + (which * GB + pt) * 4 + t] = tanhf(sv);
        }
    }
}

// ---------------------------------------------------------------------------
// Kernel 2: one block per batch element.  Stage the full 4-layer S table
// (12 KiB at GS=8) in LDS, keep qf/pf (48 floats each) in LDS, run the 4
// sequential symmetrized matvec updates, add interpolated biases, write both
// outputs.  Thread t owns ordered pair (i = t>>4, j = t&15).
// LDS ~13.6 KiB -> 8 blocks/CU (wave-capped), all 1024 blocks resident.
// ---------------------------------------------------------------------------
__global__ __launch_bounds__(256) void three_body_main(
    const float* __restrict__ q, const float* __restrict__ p,
    const float* __restrict__ m, const float* __restrict__ dtp,
    const float* __restrict__ ws, float* __restrict__ out)
{
    const int t = threadIdx.x;
    const int b = blockIdx.x;

    __shared__ float tab[4 * GS * GS * 12];   // 12 KiB
    __shared__ float mv[16];
    __shared__ float vq[48], vp[48];
    __shared__ float dbuf[48];
    __shared__ float tbuf[4][48];

    // stage table (3072 floats = 768 float4)
    {
        const float4* s4 = (const float4*)ws;
        float4*       d4 = (float4*)tab;
        #pragma unroll
        for (int k = 0; k < 3; k++) d4[t + 256 * k] = s4[t + 256 * k];
    }
    if (t < 16) mv[t] = m[b * 16 + t];
    if (t < 48) { vq[t] = q[b * 48 + t]; vp[t] = p[b * 48 + t]; }
    __syncthreads();

    const float dt    = dtp[0];
    const float scale = dt * dt * dt;

    const int i = t >> 4, j = t & 15;
    const float mi = mv[i], mj = mv[j];

    // bilinear coords: table axis a = first MLP input = m_j, axis b = m_i
    float txa = mj * (float)(GS - 1);
    int   ga  = (int)txa; if (ga > GS - 2) ga = GS - 2;
    float fa  = txa - (float)ga;
    float txb = mi * (float)(GS - 1);
    int   gb  = (int)txb; if (gb > GS - 2) gb = GS - 2;
    float fb  = txb - (float)gb;
    const float w00 = (1.0f - fa) * (1.0f - fb);
    const float w10 = fa * (1.0f - fb);
    const float w01 = (1.0f - fa) * fb;
    const float w11 = fa * fb;
    const int base = (ga * GS + gb) * 12;

    for (int l = 0; l < 4; l++) {
        const float* tl = tab + l * GS * GS * 12;
        const float4* c00 = (const float4*)(tl + base);
        const float4* c10 = (const float4*)(tl + base + GS * 12);
        const float4* c01 = (const float4*)(tl + base + 12);
        const float4* c11 = (const float4*)(tl + base + GS * 12 + 12);

        float O[12];
        #pragma unroll
        for (int u = 0; u < 3; u++) {
            float4 a0 = c00[u], a1 = c10[u], a2 = c01[u], a3 = c11[u];
            O[4 * u + 0] = w00 * a0.x + w10 * a1.x + w01 * a2.x + w11 * a3.x;
            O[4 * u + 1] = w00 * a0.y + w10 * a1.y + w01 * a2.y + w11 * a3.y;
            O[4 * u + 2] = w00 * a0.z + w10 * a1.z + w01 * a2.z + w11 * a3.z;
            O[4 * u + 3] = w00 * a0.w + w10 * a1.w + w01 * a2.w + w11 * a3.w;
        }

        const float* v = (l & 1) ? vp : vq;   // even layer updates pf from qf
        float vj0 = v[3 * j], vj1 = v[3 * j + 1], vj2 = v[3 * j + 2];
        float vi0 = v[3 * i], vi1 = v[3 * i + 1], vi2 = v[3 * i + 2];

        // direct: rows of i      d[a]  = sum_c O[3a+c] * v[3j+c]
        float d0 = O[0] * vj0 + O[1] * vj1 + O[2] * vj2;
        float d1 = O[3] * vj0 + O[4] * vj1 + O[5] * vj2;
        float d2 = O[6] * vj0 + O[7] * vj1 + O[8] * vj2;
        // transpose: rows of j   tr[c] = sum_a O[3a+c] * v[3i+a]
        float r0 = O[0] * vi0 + O[3] * vi1 + O[6] * vi2;
        float r1 = O[1] * vi0 + O[4] * vi1 + O[7] * vi2;
        float r2 = O[2] * vi0 + O[5] * vi1 + O[8] * vi2;

        // reduce d over the 16 consecutive j-lanes
        #pragma unroll
        for (int off = 1; off < 16; off <<= 1) {
            d0 += __shfl_xor(d0, off);
            d1 += __shfl_xor(d1, off);
            d2 += __shfl_xor(d2, off);
        }
        // reduce tr over the 4 i-values within this wave
        #pragma unroll
        for (int off = 16; off < 64; off <<= 1) {
            r0 += __shfl_xor(r0, off);
            r1 += __shfl_xor(r1, off);
            r2 += __shfl_xor(r2, off);
        }

        if (j == 0) { dbuf[3 * i] = d0; dbuf[3 * i + 1] = d1; dbuf[3 * i + 2] = d2; }
        const int wave = t >> 6;
        if (((t >> 4) & 3) == 0) {
            tbuf[wave][3 * j] = r0; tbuf[wave][3 * j + 1] = r1; tbuf[wave][3 * j + 2] = r2;
        }
        __syncthreads();

        float* dst = (l & 1) ? vq : vp;
        if (t < 48)
            dst[t] += scale * (dbuf[t] + tbuf[0][t] + tbuf[1][t] + tbuf[2][t] + tbuf[3][t]);
        __syncthreads();
    }

    // epilogue: add interpolated biases and write both outputs
    if (t < 96) {
        const int half = t / 48;          // 0 -> q output (bq), 1 -> p output (bp)
        const int r    = t % 48;
        const int pp   = r / 3, e = r % 3;
        float mm = mv[pp];
        float tx = mm * (float)(GB - 1);
        int   g  = (int)tx; if (g > GB - 2) g = GB - 2;
        float f  = tx - (float)g;
        const float* tb = ws + SOFF + half * GB * 4;
        float v0 = tb[g * 4 + e], v1 = tb[(g + 1) * 4 + e];
        float bias = v0 + f * (v1 - v0);
        float base_v = half ? vp[r] : vq[r];
        out[half * 49152 + b * 48 + r] = base_v + scale * bias;
    }
}

extern "C" void kernel_launch(void* const* d_in, const int* in_sizes, int n_in,
                              void* d_out, int out_size, void* d_ws, size_t ws_size,
                              hipStream_t stream) {
    const float* q   = (const float*)d_in[0];
    const float* p   = (const float*)d_in[1];
    const float* m   = (const float*)d_in[2];
    const float* dt  = (const float*)d_in[3];
    const float* sW0 = (const float*)d_in[4];
    const float* sb0 = (const float*)d_in[5];
    const float* sW1 = (const float*)d_in[6];
    const float* sb1 = (const float*)d_in[7];
    const float* sW2 = (const float*)d_in[8];
    const float* sb2 = (const float*)d_in[9];
    const float* qW0 = (const float*)d_in[10];
    const float* qb0 = (const float*)d_in[11];
    const float* qW1 = (const float*)d_in[12];
    const float* qb1 = (const float*)d_in[13];
    const float* qW2 = (const float*)d_in[14];
    const float* qb2 = (const float*)d_in[15];
    const float* kW0 = (const float*)d_in[16];
    const float* kb0 = (const float*)d_in[17];
    const float* kW1 = (const float*)d_in[18];
    const float* kb1 = (const float*)d_in[19];
    const float* kW2 = (const float*)d_in[20];
    const float* kb2 = (const float*)d_in[21];

    float* ws  = (float*)d_ws;
    float* out = (float*)d_out;

    // 256 S-table blocks (one grid point each) + 128 bias-table blocks
    build_tables<<<384, 256, 0, stream>>>(sW0, sb0, sW1, sb1, sW2, sb2,
                                          qW0, qb0, qW1, qb1, qW2, qb2,
                                          kW0, kb0, kW1, kb1, kW2, kb2, ws);
    three_body_main<<<1024, 256, 0, stream>>>(q, p, m, dt, ws, out);
}

// Round 4
// 121.737 us; speedup vs baseline: 1.0186x; 1.0186x over previous
//
#include <hip/hip_runtime.h>

#define GS   8                  // S-table grid points per axis (8x8 bilinear; err ~2e-6 in output)
#define GB   64                 // bias-table grid points
#define HDIM 256
#define SOFF (4 * GS * GS * 12) // float offset of bias tables in ws

// ---------------------------------------------------------------------------
// Kernel 1: tabulate the pair MLP S(x0,x1) on a GS x GS grid for each of the 4
// layers (entry padded to 12 floats), and the two bias MLPs bq(m), bp(m) on a
// GB grid (entry padded to 4 floats).
//
// v5 = v3 reverted: the v4 cooperative fusion never executed in the harness's
// graph-capture path (hipLaunchCooperativeKernel silently dropped; output
// stayed zero -> absmax == max|ref| == 4.125).  Two-dispatch structure is the
// correct one for this harness.
//
// Second layer is K-split across the 4 waves and vectorized: thread t =
// (s = t>>6 k-slice, g = t&63 neuron quad) loads float4 W1[k][4g..4g+3] —
// 4 iterations x 16 dwordx4 in flight.  Latency-bound, not BW-bound.
// ---------------------------------------------------------------------------
__global__ __launch_bounds__(256) void build_tables(
    const float* __restrict__ sW0, const float* __restrict__ sb0,
    const float* __restrict__ sW1, const float* __restrict__ sb1,
    const float* __restrict__ sW2, const float* __restrict__ sb2,
    const float* __restrict__ qW0, const float* __restrict__ qb0,
    const float* __restrict__ qW1, const float* __restrict__ qb1,
    const float* __restrict__ qW2, const float* __restrict__ qb2,
    const float* __restrict__ kW0, const float* __restrict__ kb0,
    const float* __restrict__ kW1, const float* __restrict__ kb1,
    const float* __restrict__ kW2, const float* __restrict__ kb2,
    float* __restrict__ ws)
{
    const int t  = threadIdx.x;
    const int bx = blockIdx.x;
    const int g  = t & 63;   // neuron quad: outputs 4g..4g+3
    const int s  = t >> 6;   // k-slice: k in [64s, 64s+64)
    const int k0 = s << 6;

    __shared__ float  h0s[HDIM];
    __shared__ float4 red2[4][64];
    __shared__ float  h1s[HDIM];
    __shared__ float  red[4][9];

    if (bx < 256) {
        // ---------------- S table: block = (layer l, grid point pt) ----------
        const int l  = bx >> 6;
        const int pt = bx & 63;
        const float* W0 = sW0 + l * 2 * HDIM;
        const float* W1 = sW1 + l * HDIM * HDIM;

        const float x0 = (float)(pt >> 3) * (1.0f / (GS - 1)); // first MLP input (m_j axis)
        const float x1 = (float)(pt & 7)  * (1.0f / (GS - 1)); // second MLP input (m_i axis)
        h0s[t] = tanhf(x0 * W0[t] + x1 * W0[HDIM + t] + sb0[l * HDIM + t]);
        __syncthreads();

        // second layer, K-split: acc4[c] = sum_{k in slice} h0[k] * W1[k][4g+c]
        float4 acc4 = make_float4(0.f, 0.f, 0.f, 0.f);
        const float* W1c = W1 + 4 * g;
        for (int kk = 0; kk < 64; kk += 16) {
            float4 w4[16];
            #pragma unroll
            for (int u = 0; u < 16; u++)
                w4[u] = *(const float4*)&W1c[(k0 + kk + u) * HDIM];
            #pragma unroll
            for (int u = 0; u < 16; u++) {
                float h = h0s[k0 + kk + u];        // wave-uniform broadcast
                acc4.x += h * w4[u].x;
                acc4.y += h * w4[u].y;
                acc4.z += h * w4[u].z;
                acc4.w += h * w4[u].w;
            }
        }
        red2[s][g] = acc4;
        __syncthreads();
        if (t < 64) {
            float4 a = red2[0][t], b = red2[1][t], c = red2[2][t], d = red2[3][t];
            float4 bb = *(const float4*)&sb1[l * HDIM + 4 * t];
            float4 h1;
            h1.x = tanhf(a.x + b.x + c.x + d.x + bb.x);
            h1.y = tanhf(a.y + b.y + c.y + d.y + bb.y);
            h1.z = tanhf(a.z + b.z + c.z + d.z + bb.z);
            h1.w = tanhf(a.w + b.w + c.w + d.w + bb.w);
            *(float4*)&h1s[4 * t] = h1;
        }
        __syncthreads();

        // third layer + block reduce
        const float h1 = h1s[t];
        float part[9];
        #pragma unroll
        for (int o = 0; o < 9; o++) part[o] = h1 * sW2[(l * HDIM + t) * 9 + o];
        #pragma unroll
        for (int off = 32; off >= 1; off >>= 1) {
            #pragma unroll
            for (int o = 0; o < 9; o++) part[o] += __shfl_xor(part[o], off);
        }
        const int wave = t >> 6;
        if ((t & 63) == 0) {
            #pragma unroll
            for (int o = 0; o < 9; o++) red[wave][o] = part[o];
        }
        __syncthreads();
        if (t < 9) {
            float sv = red[0][t] + red[1][t] + red[2][t] + red[3][t] + sb2[l * 9 + t];
            ws[((l * GS + (pt >> 3)) * GS + (pt & 7)) * 12 + t] = tanhf(sv);
        }
    } else {
        // ---------------- bias tables: bq (which=0) / bp (which=1) ----------
        const int bb    = bx - 256;
        const int which = bb >> 6;
        const int pt    = bb & 63;
        const float* W0 = which ? kW0 : qW0;
        const float* B0 = which ? kb0 : qb0;
        const float* W1 = which ? kW1 : qW1;
        const float* B1 = which ? kb1 : qb1;
        const float* W2 = which ? kW2 : qW2;
        const float* B2 = which ? kb2 : qb2;

        const float x = (float)pt * (1.0f / (GB - 1));
        h0s[t] = tanhf(x * W0[t] + B0[t]);
        __syncthreads();

        float4 acc4 = make_float4(0.f, 0.f, 0.f, 0.f);
        const float* W1c = W1 + 4 * g;
        for (int kk = 0; kk < 64; kk += 16) {
            float4 w4[16];
            #pragma unroll
            for (int u = 0; u < 16; u++)
                w4[u] = *(const float4*)&W1c[(k0 + kk + u) * HDIM];
            #pragma unroll
            for (int u = 0; u < 16; u++) {
                float h = h0s[k0 + kk + u];
                acc4.x += h * w4[u].x;
                acc4.y += h * w4[u].y;
                acc4.z += h * w4[u].z;
                acc4.w += h * w4[u].w;
            }
        }
        red2[s][g] = acc4;
        __syncthreads();
        if (t < 64) {
            float4 a = red2[0][t], b = red2[1][t], c = red2[2][t], d = red2[3][t];
            float4 bbv = *(const float4*)&B1[4 * t];
            float4 h1;
            h1.x = tanhf(a.x + b.x + c.x + d.x + bbv.x);
            h1.y = tanhf(a.y + b.y + c.y + d.y + bbv.y);
            h1.z = tanhf(a.z + b.z + c.z + d.z + bbv.z);
            h1.w = tanhf(a.w + b.w + c.w + d.w + bbv.w);
            *(float4*)&h1s[4 * t] = h1;
        }
        __syncthreads();

        const float h1 = h1s[t];
        float part[3];
        #pragma unroll
        for (int o = 0; o < 3; o++) part[o] = h1 * W2[t * 3 + o];
        #pragma unroll
        for (int off = 32; off >= 1; off >>= 1) {
            #pragma unroll
            for (int o = 0; o < 3; o++) part[o] += __shfl_xor(part[o], off);
        }
        const int wave = t >> 6;
        if ((t & 63) == 0) {
            #pragma unroll
            for (int o = 0; o < 3; o++) red[wave][o] = part[o];
        }
        __syncthreads();
        if (t < 3) {
            float sv = red[0][t] + red[1][t] + red[2][t] + red[3][t] + B2[t];
            ws[SOFF + (which * GB + pt) * 4 + t] = tanhf(sv);
        }
    }
}

// ---------------------------------------------------------------------------
// Kernel 2: one block per batch element.  Stage the full 4-layer S table
// (12 KiB at GS=8) in LDS, keep qf/pf (48 floats each) in LDS, run the 4
// sequential symmetrized matvec updates, add interpolated biases, write both
// outputs.  Thread t owns ordered pair (i = t>>4, j = t&15).
// LDS ~13.6 KiB -> 8 blocks/CU (wave-capped), all 1024 blocks resident.
// ---------------------------------------------------------------------------
__global__ __launch_bounds__(256) void three_body_main(
    const float* __restrict__ q, const float* __restrict__ p,
    const float* __restrict__ m, const float* __restrict__ dtp,
    const float* __restrict__ ws, float* __restrict__ out)
{
    const int t = threadIdx.x;
    const int b = blockIdx.x;

    __shared__ float tab[4 * GS * GS * 12];   // 12 KiB
    __shared__ float mv[16];
    __shared__ float vq[48], vp[48];
    __shared__ float dbuf[48];
    __shared__ float tbuf[4][48];

    // stage table (3072 floats = 768 float4)
    {
        const float4* s4 = (const float4*)ws;
        float4*       d4 = (float4*)tab;
        #pragma unroll
        for (int k = 0; k < 3; k++) d4[t + 256 * k] = s4[t + 256 * k];
    }
    if (t < 16) mv[t] = m[b * 16 + t];
    if (t < 48) { vq[t] = q[b * 48 + t]; vp[t] = p[b * 48 + t]; }
    __syncthreads();

    const float dt    = dtp[0];
    const float scale = dt * dt * dt;

    const int i = t >> 4, j = t & 15;
    const float mi = mv[i], mj = mv[j];

    // bilinear coords: table axis a = first MLP input = m_j, axis b = m_i
    float txa = mj * (float)(GS - 1);
    int   ga  = (int)txa; if (ga > GS - 2) ga = GS - 2;
    float fa  = txa - (float)ga;
    float txb = mi * (float)(GS - 1);
    int   gb  = (int)txb; if (gb > GS - 2) gb = GS - 2;
    float fb  = txb - (float)gb;
    const float w00 = (1.0f - fa) * (1.0f - fb);
    const float w10 = fa * (1.0f - fb);
    const float w01 = (1.0f - fa) * fb;
    const float w11 = fa * fb;
    const int base = (ga * GS + gb) * 12;

    for (int l = 0; l < 4; l++) {
        const float* tl = tab + l * GS * GS * 12;
        const float4* c00 = (const float4*)(tl + base);
        const float4* c10 = (const float4*)(tl + base + GS * 12);
        const float4* c01 = (const float4*)(tl + base + 12);
        const float4* c11 = (const float4*)(tl + base + GS * 12 + 12);

        float O[12];
        #pragma unroll
        for (int u = 0; u < 3; u++) {
            float4 a0 = c00[u], a1 = c10[u], a2 = c01[u], a3 = c11[u];
            O[4 * u + 0] = w00 * a0.x + w10 * a1.x + w01 * a2.x + w11 * a3.x;
            O[4 * u + 1] = w00 * a0.y + w10 * a1.y + w01 * a2.y + w11 * a3.y;
            O[4 * u + 2] = w00 * a0.z + w10 * a1.z + w01 * a2.z + w11 * a3.z;
            O[4 * u + 3] = w00 * a0.w + w10 * a1.w + w01 * a2.w + w11 * a3.w;
        }

        const float* v = (l & 1) ? vp : vq;   // even layer updates pf from qf
        float vj0 = v[3 * j], vj1 = v[3 * j + 1], vj2 = v[3 * j + 2];
        float vi0 = v[3 * i], vi1 = v[3 * i + 1], vi2 = v[3 * i + 2];

        // direct: rows of i      d[a]  = sum_c O[3a+c] * v[3j+c]
        float d0 = O[0] * vj0 + O[1] * vj1 + O[2] * vj2;
        float d1 = O[3] * vj0 + O[4] * vj1 + O[5] * vj2;
        float d2 = O[6] * vj0 + O[7] * vj1 + O[8] * vj2;
        // transpose: rows of j   tr[c] = sum_a O[3a+c] * v[3i+a]
        float r0 = O[0] * vi0 + O[3] * vi1 + O[6] * vi2;
        float r1 = O[1] * vi0 + O[4] * vi1 + O[7] * vi2;
        float r2 = O[2] * vi0 + O[5] * vi1 + O[8] * vi2;

        // reduce d over the 16 consecutive j-lanes
        #pragma unroll
        for (int off = 1; off < 16; off <<= 1) {
            d0 += __shfl_xor(d0, off);
            d1 += __shfl_xor(d1, off);
            d2 += __shfl_xor(d2, off);
        }
        // reduce tr over the 4 i-values within this wave
        #pragma unroll
        for (int off = 16; off < 64; off <<= 1) {
            r0 += __shfl_xor(r0, off);
            r1 += __shfl_xor(r1, off);
            r2 += __shfl_xor(r2, off);
        }

        if (j == 0) { dbuf[3 * i] = d0; dbuf[3 * i + 1] = d1; dbuf[3 * i + 2] = d2; }
        const int wave = t >> 6;
        if (((t >> 4) & 3) == 0) {
            tbuf[wave][3 * j] = r0; tbuf[wave][3 * j + 1] = r1; tbuf[wave][3 * j + 2] = r2;
        }
        __syncthreads();

        float* dst = (l & 1) ? vq : vp;
        if (t < 48)
            dst[t] += scale * (dbuf[t] + tbuf[0][t] + tbuf[1][t] + tbuf[2][t] + tbuf[3][t]);
        __syncthreads();
    }

    // epilogue: add interpolated biases and write both outputs
    if (t < 96) {
        const int half = t / 48;          // 0 -> q output (bq), 1 -> p output (bp)
        const int r    = t % 48;
        const int pp   = r / 3, e = r % 3;
        float mm = mv[pp];
        float tx = mm * (float)(GB - 1);
        int   g  = (int)tx; if (g > GB - 2) g = GB - 2;
        float f  = tx - (float)g;
        const float* tb = ws + SOFF + half * GB * 4;
        float v0 = tb[g * 4 + e], v1 = tb[(g + 1) * 4 + e];
        float bias = v0 + f * (v1 - v0);
        float base_v = half ? vp[r] : vq[r];
        out[half * 49152 + b * 48 + r] = base_v + scale * bias;
    }
}

extern "C" void kernel_launch(void* const* d_in, const int* in_sizes, int n_in,
                              void* d_out, int out_size, void* d_ws, size_t ws_size,
                              hipStream_t stream) {
    const float* q   = (const float*)d_in[0];
    const float* p   = (const float*)d_in[1];
    const float* m   = (const float*)d_in[2];
    const float* dt  = (const float*)d_in[3];
    const float* sW0 = (const float*)d_in[4];
    const float* sb0 = (const float*)d_in[5];
    const float* sW1 = (const float*)d_in[6];
    const float* sb1 = (const float*)d_in[7];
    const float* sW2 = (const float*)d_in[8];
    const float* sb2 = (const float*)d_in[9];
    const float* qW0 = (const float*)d_in[10];
    const float* qb0 = (const float*)d_in[11];
    const float* qW1 = (const float*)d_in[12];
    const float* qb1 = (const float*)d_in[13];
    const float* qW2 = (const float*)d_in[14];
    const float* qb2 = (const float*)d_in[15];
    const float* kW0 = (const float*)d_in[16];
    const float* kb0 = (const float*)d_in[17];
    const float* kW1 = (const float*)d_in[18];
    const float* kb1 = (const float*)d_in[19];
    const float* kW2 = (const float*)d_in[20];
    const float* kb2 = (const float*)d_in[21];

    float* ws  = (float*)d_ws;
    float* out = (float*)d_out;

    // 256 S-table blocks (one grid point each) + 128 bias-table blocks
    build_tables<<<384, 256, 0, stream>>>(sW0, sb0, sW1, sb1, sW2, sb2,
                                          qW0, qb0, qW1, qb1, qW2, qb2,
                                          kW0, kb0, kW1, kb1, kW2, kb2, ws);
    three_body_main<<<1024, 256, 0, stream>>>(q, p, m, dt, ws, out);
}